// Round 4
// baseline (774.959 us; speedup 1.0000x reference)
//
#include <hip/hip_runtime.h>

#define IN_F   8192
#define OUT_F  16384
#define BATCH  32
#define KT     1024                 // codes per row per staged tile
#define NT     (IN_F / KT)          // 8 tiles per block
#define PITCH  1040                 // 1024 B row + 16 B pad (bank shift 4/row)

typedef __attribute__((ext_vector_type(8))) short  bf16x8;
typedef __attribute__((ext_vector_type(4))) float  f32x4;

// fp32 -> bf16 bits, round-to-nearest-even
__device__ __forceinline__ unsigned f2bf(float f) {
    unsigned u = __builtin_bit_cast(unsigned, f);
    return (u + 0x7fffu + ((u >> 16) & 1u)) >> 16;
}

// pack two exact-integer floats (<256) into {bf16(fb) hi, bf16(fa) lo}
__device__ __forceinline__ unsigned pk_ff(float fa, float fb) {
    unsigned ua = __builtin_bit_cast(unsigned, fa);
    unsigned ub = __builtin_bit_cast(unsigned, fb);
#if __has_builtin(__builtin_amdgcn_perm)
    return __builtin_amdgcn_perm(ub, ua, 0x07060302u);  // {ub.hi, ua.hi}
#else
    return (ua >> 16) | (ub & 0xffff0000u);
#endif
}

// low bytes of 4 ints -> one dword
__device__ __forceinline__ unsigned p4(int4 c) {
    return (c.x & 255) | ((c.y & 255) << 8) |
           ((c.z & 255) << 16) | ((unsigned)(c.w & 255) << 24);
}

// async global->LDS DMA, 16 B/lane, dest = wave-uniform base + lane*16
__device__ __forceinline__ void async_copy16(const void* g, void* l) {
    __builtin_amdgcn_global_load_lds(
        (const __attribute__((address_space(1))) unsigned*)g,
        (__attribute__((address_space(3))) unsigned*)l,
        16, 0, 0);
}

// xbf[b][k] = bf16(x[b][k] * s), sumx[b] = sum_k x[b][k];  s = lut[129]
// (lut is exactly linear: lut[c] = (c-128)*s, so codes stay integer in bf16)
__global__ __launch_bounds__(256) void prep_kernel(
        const float* __restrict__ x, const float* __restrict__ lut,
        unsigned short* __restrict__ xbf, float* __restrict__ sumx) {
    const int b = blockIdx.x;
    const int t = threadIdx.x;
    const float s = lut[129];
    const float4* xr = (const float4*)(x + b * IN_F);
    ushort4* xo = (ushort4*)(xbf + b * IN_F);
    float acc = 0.f;
    #pragma unroll
    for (int i = 0; i < IN_F / 4 / 256; ++i) {
        float4 v = xr[t + i * 256];
        acc += v.x + v.y + v.z + v.w;
        ushort4 o;
        o.x = (unsigned short)f2bf(v.x * s);
        o.y = (unsigned short)f2bf(v.y * s);
        o.z = (unsigned short)f2bf(v.z * s);
        o.w = (unsigned short)f2bf(v.w * s);
        xo[t + i * 256] = o;
    }
    __shared__ float red[256];
    red[t] = acc;
    __syncthreads();
    for (int off = 128; off > 0; off >>= 1) {
        if (t < off) red[t] += red[t + off];
        __syncthreads();
    }
    if (t == 0) sumx[b] = red[0];
}

// Pure linear memcpy-with-narrowing: wpk[i] = (uint8)widx[i] (row-major
// order PRESERVED; out byte index == in int index). One block = 8 rows =
// one contiguous 256 KB read stream -> one contiguous 64 KB write stream.
// 1 stream per block (2048 blocks) instead of 16K strided streams: DRAM
// page-friendly on both sides. Reads 1 KB/instr coalesced.
__global__ __launch_bounds__(256) void pack_kernel(
        const int* __restrict__ widx, unsigned char* __restrict__ wpk) {
    const int tid = threadIdx.x;
    const long base = (long)blockIdx.x * (8 * IN_F);   // ints
    const int4* s4 = (const int4*)(widx + base);
    unsigned*   dd = (unsigned*)(wpk + base);          // 1 B/int: same index
    #pragma unroll 2
    for (int it = 0; it < 16; ++it) {
        int4 c[4];
        #pragma unroll
        for (int q = 0; q < 4; ++q)
            c[q] = s4[it * 1024 + q * 256 + tid];      // 1 KB contiguous/instr
        #pragma unroll
        for (int q = 0; q < 4; ++q)
            dd[it * 1024 + q * 256 + tid] = p4(c[q]);  // 256 B contiguous/instr
    }
}

// One block per 16-row n-tile, full K. Stages uint8 codes from wpk (row-major,
// so the block's slab is a 128 KB contiguous region just written by pack ->
// L2/L3-hot). 16 KB/tile via 16 DMA instrs (1 KB each), double-buffered with
// counted vmcnt(4) + raw s_barrier so next-tile loads stay in flight across
// the barrier (no vmcnt(0) drain in steady state).
// MFMA 16x16x32 bf16: A[m=lane&15][k=(lane>>4)*8+j], C/D col=lane&15,
// row=(lane>>4)*4+reg (validated in earlier rounds).
__global__ __launch_bounds__(256, 4) void gemm_kernel(
        const unsigned short* __restrict__ xbf,
        const unsigned char* __restrict__ wpk,
        const float* __restrict__ bias,
        const float* __restrict__ lut,
        const float* __restrict__ sumx,
        float* __restrict__ out) {
    __shared__ char ltile[2][16 * PITCH];        // 2 x 16,640 B = 33,280 B
    const int tid   = threadIdx.x;
    const int wave  = tid >> 6;
    const int lane  = tid & 63;
    const int col16 = lane & 15;
    const int quad  = lane >> 4;
    const int n0    = blockIdx.x * 16;

    const unsigned char* slab = wpk + (long)n0 * IN_F;          // 128 KB region
    const unsigned short* xp0 = xbf + col16 * IN_F + quad * 8;  // m = col16
    const unsigned short* xp1 = xp0 + 16 * IN_F;                // m = col16+16

    f32x4 acc0 = {0.f, 0.f, 0.f, 0.f};
    f32x4 acc1 = {0.f, 0.f, 0.f, 0.f};

    // stage tile tt into buffer bb: wave w DMAs rows w*4..w*4+3 (1 KB each)
    #define STAGE(tt, bb)                                                     \
        _Pragma("unroll")                                                     \
        for (int j = 0; j < 4; ++j) {                                         \
            const int r_ = wave * 4 + j;                                      \
            async_copy16(slab + (long)r_ * IN_F + (tt) * KT + lane * 16,      \
                         &ltile[bb][r_ * PITCH]);                             \
        }

    STAGE(0, 0)
    for (int t = 0; t < NT; ++t) {
        if (t < NT - 1) {
            STAGE(t + 1, (t + 1) & 1)
            asm volatile("s_waitcnt vmcnt(4)" ::: "memory");  // tile t landed (own)
        } else {
            asm volatile("s_waitcnt vmcnt(0)" ::: "memory");
        }
        asm volatile("s_barrier" ::: "memory");               // all waves' tile t in LDS
        // compute: wave w consumes k sub-range [w*256, w*256+256) of the tile
        const char* base = &ltile[t & 1][col16 * PITCH + wave * 256 + quad * 8];
        #pragma unroll
        for (int s = 0; s < 8; ++s) {
            unsigned p0 = *(const unsigned*)(base + s * 32);
            unsigned p1 = *(const unsigned*)(base + s * 32 + 4);
            const int ka = t * KT + wave * 256 + s * 32;
            bf16x8 a0 = *(const bf16x8*)(xp0 + ka);
            bf16x8 a1 = *(const bf16x8*)(xp1 + ka);
            float f0 = (float)(p0 & 255u),         f1 = (float)((p0 >> 8) & 255u);
            float f2 = (float)((p0 >> 16) & 255u), f3 = (float)(p0 >> 24);
            float f4 = (float)(p1 & 255u),         f5 = (float)((p1 >> 8) & 255u);
            float f6 = (float)((p1 >> 16) & 255u), f7 = (float)(p1 >> 24);
            union { unsigned u[4]; bf16x8 v; } bB;
            bB.u[0] = pk_ff(f0, f1);
            bB.u[1] = pk_ff(f2, f3);
            bB.u[2] = pk_ff(f4, f5);
            bB.u[3] = pk_ff(f6, f7);
            acc0 = __builtin_amdgcn_mfma_f32_16x16x32_bf16(a0, bB.v, acc0, 0, 0, 0);
            acc1 = __builtin_amdgcn_mfma_f32_16x16x32_bf16(a1, bB.v, acc1, 0, 0, 0);
        }
        asm volatile("s_barrier" ::: "memory");  // done reading before overwrite
    }

    // epilogue: cross-wave (split-k within block) reduce via LDS, fuse
    // bias + lut[0]*sumx correction, direct store (out fully overwritten).
    float* red = (float*)ltile;                  // 4 x 512 floats = 8 KB
    #pragma unroll
    for (int r = 0; r < 4; ++r) {
        red[wave * 512 + (quad * 4 + r)      * 16 + col16] = acc0[r];
        red[wave * 512 + (quad * 4 + r + 16) * 16 + col16] = acc1[r];
    }
    __syncthreads();
    const float l0 = lut[0];                     // = -128*s
    #pragma unroll
    for (int e0 = 0; e0 < 2; ++e0) {
        const int e = tid + e0 * 256;            // 512 elems = 32 m x 16 n
        float v = red[e] + red[e + 512] + red[e + 1024] + red[e + 1536];
        const int m  = e >> 4;
        const int nn = e & 15;
        v += bias[n0 + nn] + l0 * sumx[m];
        out[(long)m * OUT_F + n0 + nn] = v;
    }
}

extern "C" void kernel_launch(void* const* d_in, const int* in_sizes, int n_in,
                              void* d_out, int out_size, void* d_ws, size_t ws_size,
                              hipStream_t stream) {
    const float* x    = (const float*)d_in[0];
    const float* lut  = (const float*)d_in[1];
    const float* bias = (const float*)d_in[2];
    const int*   widx = (const int*)d_in[3];
    float* out = (float*)d_out;

    unsigned short* xbf = (unsigned short*)d_ws;                    // 512 KiB
    float* sumx = (float*)((char*)d_ws + BATCH * IN_F * 2);         // 128 B
    unsigned char* wpk = (unsigned char*)d_ws + (1 << 20);          // 128 MiB packed codes

    prep_kernel<<<BATCH, 256, 0, stream>>>(x, lut, xbf, sumx);
    pack_kernel<<<OUT_F / 8, 256, 0, stream>>>(widx, wpk);
    gemm_kernel<<<OUT_F / 16, 256, 0, stream>>>(xbf, wpk, bias, lut, sumx, out);
}

// Round 5
// 683.866 us; speedup vs baseline: 1.1332x; 1.1332x over previous
//
#include <hip/hip_runtime.h>

#define IN_F   8192
#define OUT_F  16384
#define BATCH  32
#define KT     256                  // int32 codes per row per staged tile (1 KB)
#define NT     (IN_F / KT)          // 32 tiles
#define PITCH  1040                 // 1024 B row + 16 B pad (16-mult; bank shift 4/row)

typedef __attribute__((ext_vector_type(8))) short  bf16x8;
typedef __attribute__((ext_vector_type(4))) float  f32x4;

// fp32 -> bf16 bits, round-to-nearest-even
__device__ __forceinline__ unsigned f2bf(float f) {
    unsigned u = __builtin_bit_cast(unsigned, f);
    return (u + 0x7fffu + ((u >> 16) & 1u)) >> 16;
}

// pack two exact-integer floats (<256) into {bf16(fb) hi, bf16(fa) lo}
__device__ __forceinline__ unsigned pk_i2bf(int a, int b) {
    unsigned fa = __builtin_bit_cast(unsigned, (float)a);
    unsigned fb = __builtin_bit_cast(unsigned, (float)b);
#if __has_builtin(__builtin_amdgcn_perm)
    return __builtin_amdgcn_perm(fb, fa, 0x07060302u);  // {fb.hi, fa.hi}
#else
    return (fa >> 16) | (fb & 0xffff0000u);
#endif
}

// async global->LDS DMA, 16 B/lane, dest = wave-uniform base + lane*16
__device__ __forceinline__ void async_copy16(const void* g, void* l) {
    __builtin_amdgcn_global_load_lds(
        (const __attribute__((address_space(1))) unsigned*)g,
        (__attribute__((address_space(3))) unsigned*)l,
        16, 0, 0);
}

// xbf[b][k] = bf16(x[b][k] * s), sumx[b] = sum_k x[b][k];  s = lut[129]
// (lut is exactly linear: lut[c] = (c-128)*s, so codes stay integer in bf16)
__global__ __launch_bounds__(256) void prep_kernel(
        const float* __restrict__ x, const float* __restrict__ lut,
        unsigned short* __restrict__ xbf, float* __restrict__ sumx) {
    const int b = blockIdx.x;
    const int t = threadIdx.x;
    const float s = lut[129];
    const float4* xr = (const float4*)(x + b * IN_F);
    ushort4* xo = (ushort4*)(xbf + b * IN_F);
    float acc = 0.f;
    #pragma unroll
    for (int i = 0; i < IN_F / 4 / 256; ++i) {
        float4 v = xr[t + i * 256];
        acc += v.x + v.y + v.z + v.w;
        ushort4 o;
        o.x = (unsigned short)f2bf(v.x * s);
        o.y = (unsigned short)f2bf(v.y * s);
        o.z = (unsigned short)f2bf(v.z * s);
        o.w = (unsigned short)f2bf(v.w * s);
        xo[t + i * 256] = o;
    }
    __shared__ float red[256];
    red[t] = acc;
    __syncthreads();
    for (int off = 128; off > 0; off >>= 1) {
        if (t < off) red[t] += red[t + off];
        __syncthreads();
    }
    if (t == 0) sumx[b] = red[0];
}

// One block per 16-row n-tile, full K, reading int32 widx directly (no pack
// pre-pass: pack cost > gemm savings, measured R2 vs R3/R4). Double-buffered
// LDS W-tiles via global_load_lds; A-fragments software-pipelined in REGISTERS
// one tile ahead, issued in the same group as the W-DMAs. Steady state per
// tile: [DMA(t+1) x4, aload(t+1) x4] -> vmcnt(8) -> s_barrier -> compute(t).
// vmcnt(8) retires exactly tile t's 8 vmem ops and keeps tile t+1's 8 in
// flight; the compiler's pre-MFMA wait for A-regs is >= vmcnt(8) by issue
// order, so the prefetch is NEVER drained (the defect in rounds 0-4: in-loop
// A-loads forced a vmcnt(0)-equivalent drain of the DMA queue every tile).
// MFMA 16x16x32 bf16: A[m=lane&15][k=(lane>>4)*8+j], C/D col=lane&15,
// row=(lane>>4)*4+reg (validated in earlier rounds).
__global__ __launch_bounds__(256, 4) void gemm_kernel(
        const unsigned short* __restrict__ xbf,
        const int* __restrict__ widx,
        const float* __restrict__ bias,
        const float* __restrict__ lut,
        const float* __restrict__ sumx,
        float* __restrict__ out) {
    __shared__ char ltile[2][16 * PITCH];        // 2 x 16,640 B = 33,280 B
    const int tid   = threadIdx.x;
    const int wave  = tid >> 6;
    const int lane  = tid & 63;
    const int col16 = lane & 15;
    const int quad  = lane >> 4;
    const int n0    = blockIdx.x * 16;

    const int* slab = widx + (long)n0 * IN_F;
    const unsigned short* xp0 = xbf + col16 * IN_F + quad * 8;  // m = col16
    const unsigned short* xp1 = xp0 + 16 * IN_F;                // m = col16+16

    f32x4 acc0 = {0.f, 0.f, 0.f, 0.f};
    f32x4 acc1 = {0.f, 0.f, 0.f, 0.f};

    // stage W-tile tt into buffer bb: wave w DMAs rows w*4..w*4+3 (1 KB each)
    #define STAGE(tt, bb)                                                     \
        _Pragma("unroll")                                                     \
        for (int j_ = 0; j_ < 4; ++j_) {                                      \
            const int r_ = wave * 4 + j_;                                     \
            async_copy16(slab + (long)r_ * IN_F + (tt) * KT + lane * 4,       \
                         &ltile[bb][r_ * PITCH]);                             \
        }

    // A-fragment register prefetch for tile tt: {m0s0, m1s0, m0s1, m1s1}
    #define ALOAD(dst, tt)                                                    \
        do {                                                                  \
            const int ka_ = (tt) * KT + wave * 64;                            \
            dst[0] = *(const bf16x8*)(xp0 + ka_);                             \
            dst[1] = *(const bf16x8*)(xp1 + ka_);                             \
            dst[2] = *(const bf16x8*)(xp0 + ka_ + 32);                        \
            dst[3] = *(const bf16x8*)(xp1 + ka_ + 32);                        \
        } while (0)

    // compute tile tt from buffer bb with A-register set ar
    #define COMPUTE(tt, bb, ar)                                               \
        _Pragma("unroll")                                                     \
        for (int s_ = 0; s_ < 2; ++s_) {                                      \
            const char* b_ = &ltile[bb][col16 * PITCH + wave * 256            \
                                        + s_ * 128 + quad * 32];              \
            int4 c0 = *(const int4*)(b_);                                     \
            int4 c1 = *(const int4*)(b_ + 16);                                \
            union { unsigned u[4]; bf16x8 v; } bB;                            \
            bB.u[0] = pk_i2bf(c0.x, c0.y);                                    \
            bB.u[1] = pk_i2bf(c0.z, c0.w);                                    \
            bB.u[2] = pk_i2bf(c1.x, c1.y);                                    \
            bB.u[3] = pk_i2bf(c1.z, c1.w);                                    \
            acc0 = __builtin_amdgcn_mfma_f32_16x16x32_bf16(                   \
                       ar[s_ * 2],     bB.v, acc0, 0, 0, 0);                  \
            acc1 = __builtin_amdgcn_mfma_f32_16x16x32_bf16(                   \
                       ar[s_ * 2 + 1], bB.v, acc1, 0, 0, 0);                  \
        }

    bf16x8 aE[4], aO[4];            // even-tile / odd-tile A registers
    STAGE(0, 0)
    ALOAD(aE, 0);

    #pragma unroll
    for (int t = 0; t < NT; t += 2) {
        // ---- even tile t (buffer 0, regs aE) ----
        if (t + 1 < NT) {
            STAGE(t + 1, 1)
            ALOAD(aO, t + 1);
            asm volatile("s_waitcnt vmcnt(8)" ::: "memory");  // tile t landed
        } else {
            asm volatile("s_waitcnt vmcnt(0)" ::: "memory");
        }
        __builtin_amdgcn_s_barrier();
        COMPUTE(t, 0, aE)
        __builtin_amdgcn_s_barrier();
        // ---- odd tile t+1 (buffer 1, regs aO) ----
        if (t + 2 < NT) {
            STAGE(t + 2, 0)
            ALOAD(aE, t + 2);
            asm volatile("s_waitcnt vmcnt(8)" ::: "memory");  // tile t+1 landed
        } else {
            asm volatile("s_waitcnt vmcnt(0)" ::: "memory");
        }
        __builtin_amdgcn_s_barrier();
        COMPUTE(t + 1, 1, aO)
        __builtin_amdgcn_s_barrier();
    }

    // epilogue: cross-wave (split-k within block) reduce via LDS, fuse
    // bias + lut[0]*sumx correction, direct store (out fully overwritten).
    float* red = (float*)ltile;                  // 4 x 512 floats = 8 KB
    #pragma unroll
    for (int r = 0; r < 4; ++r) {
        red[wave * 512 + (quad * 4 + r)      * 16 + col16] = acc0[r];
        red[wave * 512 + (quad * 4 + r + 16) * 16 + col16] = acc1[r];
    }
    __syncthreads();
    const float l0 = lut[0];                     // = -128*s
    #pragma unroll
    for (int e0 = 0; e0 < 2; ++e0) {
        const int e = tid + e0 * 256;            // 512 elems = 32 m x 16 n
        float v = red[e] + red[e + 512] + red[e + 1024] + red[e + 1536];
        const int m  = e >> 4;
        const int nn = e & 15;
        v += bias[n0 + nn] + l0 * sumx[m];
        out[(long)m * OUT_F + n0 + nn] = v;
    }
}

extern "C" void kernel_launch(void* const* d_in, const int* in_sizes, int n_in,
                              void* d_out, int out_size, void* d_ws, size_t ws_size,
                              hipStream_t stream) {
    const float* x    = (const float*)d_in[0];
    const float* lut  = (const float*)d_in[1];
    const float* bias = (const float*)d_in[2];
    const int*   widx = (const int*)d_in[3];
    float* out = (float*)d_out;

    unsigned short* xbf = (unsigned short*)d_ws;                    // 512 KiB
    float* sumx = (float*)((char*)d_ws + BATCH * IN_F * 2);         // 128 B

    prep_kernel<<<BATCH, 256, 0, stream>>>(x, lut, xbf, sumx);
    gemm_kernel<<<OUT_F / 16, 256, 0, stream>>>(xbf, widx, bias, lut, sumx, out);
}